// Round 3
// baseline (373.925 us; speedup 1.0000x reference)
//
#include <hip/hip_runtime.h>
#include <math.h>

#define S_DIM 8
#define N_DIM 2048
#define K_DIM 64
#define APW 4          // atoms per wave (= per 64-thread block)
#define ST_ST 40       // s_tilde row stride, bf16 units (80 B rows, 16B-aligned)
#define ST_H1 72       // h1 chunk row stride, bf16 units (144 B rows, 16B-aligned)

typedef __attribute__((ext_vector_type(8))) short bf16x8;
typedef __attribute__((ext_vector_type(4))) float f32x4;
typedef __attribute__((ext_vector_type(4))) int   i32x4;

__device__ __forceinline__ unsigned asu(float x) {
    union { float f; unsigned u; } v; v.f = x; return v.u;
}
__device__ __forceinline__ unsigned short f2bf(float x) {
    unsigned u = asu(x);
    return (unsigned short)((u + 0x7FFFu + ((u >> 16) & 1u)) >> 16);
}
__device__ __forceinline__ float bf2f(unsigned short h) {
    union { unsigned u; float f; } v; v.u = ((unsigned)h) << 16; return v.f;
}
// round-nearest-even packed pair (x -> lo16, y -> hi16) — integer-ALU form,
// bit-identical to the measured-correct round-0 baseline (absmax 128).
// v_cvt_pk_bf16_f32 was the round-2 absmax-524 suspect (rounding mode unknown
// on gfx950): reverted.
__device__ __forceinline__ unsigned rne_pk(float x, float y) {
    unsigned ux = asu(x), uy = asu(y);
    return ((ux + 0x7FFFu + ((ux >> 16) & 1u)) >> 16) |
           ((uy + 0x7FFFu + ((uy >> 16) & 1u)) & 0xFFFF0000u);
}
// truncation packed pair (cheap; used only for MFMA operand packs, as round-0)
__device__ __forceinline__ unsigned trn_pk(float x, float y) {
    return (asu(x) >> 16) | (asu(y) & 0xFFFF0000u);
}
// LDS-only fence: orders intra-wave cross-lane LDS traffic WITHOUT draining
// vmcnt. Blocks are single-wave, so __syncthreads' s_barrier + vmcnt(0) drain
// (which serialized output stores + killed gather prefetch every atom) is
// unnecessary; lgkmcnt(0) + a compiler memory barrier is sufficient.
__device__ __forceinline__ void lds_fence() {
    asm volatile("s_waitcnt lgkmcnt(0)" ::: "memory");
    __builtin_amdgcn_sched_barrier(0);
}
// K<=16 MFMA from two packed bf16-pair dwords per operand (zero-padded K=32).
__device__ __forceinline__ f32x4 mfma_k16(unsigned a0, unsigned a1,
                                          unsigned b0, unsigned b1, f32x4 c) {
    union { i32x4 i; bf16x8 b; } ua, ub;
    ua.i = (i32x4){(int)a0, (int)a1, 0, 0};
    ub.i = (i32x4){(int)b0, (int)b1, 0, 0};
    return __builtin_amdgcn_mfma_f32_16x16x32_bf16(ua.b, ub.b, c, 0, 0, 0);
}

// ---------------------------------------------------------------------------
// Prep: packed td table (4 pairs x 16 u32 of bf16-pairs) + bf16 weights.
// ---------------------------------------------------------------------------
__global__ __launch_bounds__(256) void prep_kernel(
        const float* __restrict__ ew0, const float* __restrict__ eb0,
        const float* __restrict__ ew1, const float* __restrict__ eb1,
        const float* __restrict__ fw0, const float* __restrict__ fb0,
        const float* __restrict__ fw1, const float* __restrict__ fb1,
        const float* __restrict__ gw0, const float* __restrict__ gw1,
        unsigned* __restrict__ td_pk,
        unsigned short* __restrict__ w0t, unsigned short* __restrict__ w1t) {
    __shared__ float l_ew0[32], l_eb0[16], l_ew1[512], l_eb1[32];
    __shared__ float l_fw0[1024], l_fb0[32], l_fw1[992], l_fb1[31];
    __shared__ float l_h[4][2][16];
    __shared__ float l_tv[4][32];
    __shared__ float l_f1[4][32];
    __shared__ float l_td[4][32];

    const int tid = threadIdx.x;
    if (tid < 32) l_ew0[tid] = ew0[tid];
    if (tid < 16) l_eb0[tid] = eb0[tid];
    for (int i = tid; i < 512; i += 256) l_ew1[i] = ew1[i];
    if (tid < 32) l_eb1[tid] = eb1[tid];
    for (int i = tid; i < 1024; i += 256) l_fw0[i] = fw0[i];
    if (tid < 32) l_fb0[tid] = fb0[tid];
    for (int i = tid; i < 992; i += 256) l_fw1[i] = fw1[i];
    if (tid < 31) l_fb1[tid] = fb1[tid];
    __syncthreads();

    if (tid < 128) {
        const int p = tid >> 5, ord = (tid >> 4) & 1, j = tid & 15;
        const float c = (float)(p >> 1), t = (float)(p & 1);
        const float x0 = ord ? t : c;
        const float x1 = ord ? c : t;
        l_h[p][ord][j] = fmaxf(x0 * l_ew0[j] + x1 * l_ew0[16 + j] + l_eb0[j], 0.f);
    }
    __syncthreads();
    if (tid < 128) {
        const int p = tid >> 5, j = tid & 31;
        float acc = 0.f;
#pragma unroll
        for (int ord = 0; ord < 2; ord++) {
            float v = l_eb1[j];
#pragma unroll
            for (int i = 0; i < 16; i++) v += l_h[p][ord][i] * l_ew1[i * 32 + j];
            acc += fmaxf(v, 0.f);
        }
        l_tv[p][j] = acc;
    }
    __syncthreads();
    if (tid < 128) {
        const int p = tid >> 5, j = tid & 31;
        float v = l_fb0[j];
#pragma unroll
        for (int i = 0; i < 32; i++) v += l_tv[p][i] * l_fw0[i * 32 + j];
        l_f1[p][j] = fmaxf(v, 0.f);
    }
    __syncthreads();
    if (tid < 128) {
        const int p = tid >> 5, j = tid & 31;
        if (j < 31) {
            float v = l_fb1[j];
#pragma unroll
            for (int i = 0; i < 32; i++) v += l_f1[p][i] * l_fw1[i * 31 + j];
            l_td[p][j] = fmaxf(v, 0.f);
        } else {
            l_td[p][31] = 0.f;
        }
    }
    __syncthreads();
    if (tid < 64) {   // pack: td_pk[p*16+i] = bf(td[2i]) | bf(td[2i+1])<<16
        const int p = tid >> 4, i = tid & 15;
        const unsigned lo = f2bf(l_td[p][2 * i]);
        const unsigned hi = (i == 15) ? 0u : (unsigned)f2bf(l_td[p][2 * i + 1]);
        td_pk[tid] = lo | (hi << 16);
    }

    for (int idx = tid; idx < 2048; idx += 256) {   // W0T[j*32+i] = gw0[i][j]
        const int j = idx >> 5, i = idx & 31;
        w0t[idx] = f2bf(gw0[i * 64 + j]);
    }
    for (int idx = tid; idx < 8192; idx += 256) {   // W1T[e*64+j] = gw1[j][e]
        const int e = idx >> 6, j = idx & 63;
        w1t[idx] = f2bf(gw1[j * 128 + e]);
    }
}

// ---------------------------------------------------------------------------
// Main: one wave per block, 4 atoms per wave, software-pipelined geometry.
// No __syncthreads anywhere: single-wave blocks only need LDS-order fences,
// so output stores and next-atom gathers stay in flight across atoms.
// h1 is produced/consumed in 16-row double-buffered chunks (LDS 15.9->10.7KB).
// Numerics are bit-identical to the round-0 baseline (rne_pk/f2bf/trn_pk).
// ---------------------------------------------------------------------------
__global__ __launch_bounds__(64, 3) void descr_mfma(
    const float* __restrict__ inputs, const int* __restrict__ input_types,
    const int* __restrict__ neigh_list, const float* __restrict__ length,
    const float* __restrict__ gb0, const float* __restrict__ gb1,
    const unsigned* __restrict__ td_pk, const unsigned short* __restrict__ w0t,
    const unsigned short* __restrict__ w1t, float* __restrict__ out)
{
    __shared__ __align__(16) unsigned short s_st[64 * ST_ST];      // 5.0 KB; s_A overlay
    __shared__ __align__(16) unsigned short s_h1[2][16 * ST_H1];   // 4.5 KB dbuf chunks
    __shared__ __align__(16) float s_rtT[4 * 68];                  // 1.1 KB
    __shared__ unsigned s_tdpk[64];
    float* s_A = (float*)s_st;                                     // st dead after L1

    const int lane = threadIdx.x;
    const int l15 = lane & 15;
    const int q = lane >> 4;
    const int abase = blockIdx.x * APW;
    const int sidx = abase >> 11;      // all 4 atoms of a block share the same s

    // static weight fragments (B-layout)
    bf16x8 w0f[4];
#pragma unroll
    for (int nt = 0; nt < 4; nt++)
        w0f[nt] = *(const bf16x8*)&w0t[(nt * 16 + l15) * 32 + q * 8];
    bf16x8 w1f[8][2];
#pragma unroll
    for (int et = 0; et < 8; et++) {
        w1f[et][0] = *(const bf16x8*)&w1t[(et * 16 + l15) * 64 + q * 8];
        w1f[et][1] = *(const bf16x8*)&w1t[(et * 16 + l15) * 64 + 32 + q * 8];
    }
    float b0f[4], b1f[8];
#pragma unroll
    for (int jt = 0; jt < 4; jt++) b0f[jt] = gb0[jt * 16 + l15];
#pragma unroll
    for (int et = 0; et < 8; et++) b1f[et] = gb1[et * 16 + l15];
    s_tdpk[lane] = td_pk[lane];
    const float Lx = length[0], Ly = length[1], Lz = length[2];
    const float iLx = 1.f / Lx, iLy = 1.f / Ly, iLz = 1.f / Lz;
    const f32x4 zf = {0.f, 0.f, 0.f, 0.f};

    // geometry state for the CURRENT atom (loaded one iteration ahead)
    int   cnb  = neigh_list[abase * K_DIM + lane];
    float ccx  = inputs[abase * 3 + 0];
    float ccy  = inputs[abase * 3 + 1];
    float ccz  = inputs[abase * 3 + 2];
    int   cct  = input_types[abase];
    int   cidx0 = cnb < 0 ? 0 : cnb;
    float cpx  = inputs[(sidx * N_DIM + cidx0) * 3 + 0];
    float cpy  = inputs[(sidx * N_DIM + cidx0) * 3 + 1];
    float cpz  = inputs[(sidx * N_DIM + cidx0) * 3 + 2];
    int   cntp = input_types[sidx * N_DIM + cidx0];

    for (int aa = 0; aa < APW; aa++) {
        const int atom = abase + aa;
        const bool pf = (aa + 1 < APW);

        // ---- stage-A prefetch for next atom (independent addresses, issue now)
        int nnb = 0, nct = 0; float ncx = 0.f, ncy = 0.f, ncz = 0.f;
        if (pf) {
            nnb = neigh_list[(atom + 1) * K_DIM + lane];
            ncx = inputs[(atom + 1) * 3 + 0];
            ncy = inputs[(atom + 1) * 3 + 1];
            ncz = inputs[(atom + 1) * 3 + 2];
            nct = input_types[atom + 1];
        }

        lds_fence();   // s_st/s_rtT overwrite vs previous atom's reads (incl. s_A)

        // ---- geometry (all operands already in registers)
        {
            const bool msk = cnb < 0;
            float dx = cpx - ccx;
            float dy = cpy - ccy;
            float dz = cpz - ccz;
            dx -= Lx * rintf(dx * iLx);
            dy -= Ly * rintf(dy * iLy);
            dz -= Lz * rintf(dz * iLz);
            const float rsq = dx * dx + dy * dy + dz * dz;
            const float r = sqrtf(rsq > 0.f ? rsq : 1.f);
            const float inv = 1.f / r;
            float sw;
            if (r < 6.f) sw = inv;
            else if (r < 12.f) {
                const float u = (r - 6.f) * (1.f / 6.f);
                sw = inv * (0.5f * __cosf(3.14159265358979323846f * u) + 0.5f);
            } else sw = 0.f;
            const bool valid = (!msk) && (rsq > 0.f);
            const float sij = valid ? sw : 0.f;
            const float f = sij * inv;
            s_rtT[0 * 68 + lane] = sij;
            s_rtT[1 * 68 + lane] = dx * f;
            s_rtT[2 * 68 + lane] = dy * f;
            s_rtT[3 * 68 + lane] = dz * f;

            const unsigned* tdr = &s_tdpk[(cct * 2 + cntp) * 16];
            const unsigned zmask = msk ? 0u : 0xFFFFFFFFu;
            unsigned* strow = (unsigned*)&s_st[lane * ST_ST];
#pragma unroll
            for (int i = 0; i < 15; i++) strow[i] = tdr[i] & zmask;
            strow[15] = (tdr[15] & zmask & 0xFFFFu) | (((unsigned)f2bf(sij)) << 16);
            strow[16] = 0; strow[17] = 0; strow[18] = 0; strow[19] = 0;
        }
        lds_fence();

        // ---- rt^T fragments (A-operand of Bj/AT steps), packed RNE pairs
        unsigned rtp[4][2];
#pragma unroll
        for (int a = 0; a < 4; a++) {
            const f32x4 rv = *(const f32x4*)&s_rtT[(l15 & 3) * 68 + a * 16 + q * 4];
            rtp[a][0] = rne_pk(rv[0], rv[1]);
            rtp[a][1] = rne_pk(rv[2], rv[3]);
        }

        int nidx = 0, nntp = 0; float npx = 0.f, npy = 0.f, npz = 0.f;
        f32x4 Bj[4] = {zf, zf, zf, zf};
        f32x4 AT[8] = {zf, zf, zf, zf, zf, zf, zf, zf};

        // ---- fused per-16-row chunk: L1 -> h1 chunk -> Bj ; then L2 -> AT
#pragma unroll
        for (int mt = 0; mt < 4; mt++) {
            unsigned short* h1c = s_h1[mt & 1];
            const bf16x8 afr = *(const bf16x8*)&s_st[(mt * 16 + l15) * ST_ST + q * 8];
            f32x4 c1[4];
#pragma unroll
            for (int jt = 0; jt < 4; jt++)
                c1[jt] = __builtin_amdgcn_mfma_f32_16x16x32_bf16(afr, w0f[jt], zf, 0, 0, 0);
#pragma unroll
            for (int jt = 0; jt < 4; jt++) {
                float hv[4];
#pragma unroll
                for (int reg = 0; reg < 4; reg++) {
                    const int k = mt * 16 + q * 4 + reg;
                    const float rres = bf2f(s_st[k * ST_ST + (jt & 1) * 16 + l15]);
                    hv[reg] = fmaxf(c1[jt][reg] + b0f[jt], 0.f) + rres;
                    h1c[(q * 4 + reg) * ST_H1 + jt * 16 + l15] = f2bf(hv[reg]);
                }
                Bj[jt] = mfma_k16(rtp[mt][0], rtp[mt][1],
                                  trn_pk(hv[0], hv[1]), trn_pk(hv[2], hv[3]), Bj[jt]);
            }
            // stage-B prefetch (gathers dependent on stage-A nnb): issue once,
            // ~3 chunks + D-phase of slack before consumption next iteration
            if (mt == 0 && pf) {
                nidx = nnb < 0 ? 0 : nnb;
                const int nbase = (sidx * N_DIM + nidx) * 3;
                npx = inputs[nbase + 0];
                npy = inputs[nbase + 1];
                npz = inputs[nbase + 2];
                nntp = input_types[sidx * N_DIM + nidx];
            }
            lds_fence();   // chunk write -> read handoff (dbuf: no end-of-chunk fence)

            const bf16x8 a0 = *(const bf16x8*)&h1c[l15 * ST_H1 + q * 8];
            const bf16x8 a1 = *(const bf16x8*)&h1c[l15 * ST_H1 + 32 + q * 8];
#pragma unroll
            for (int et = 0; et < 8; et++) {
                f32x4 c2 = __builtin_amdgcn_mfma_f32_16x16x32_bf16(a0, w1f[et][0], zf, 0, 0, 0);
                c2 = __builtin_amdgcn_mfma_f32_16x16x32_bf16(a1, w1f[et][1], c2, 0, 0, 0);
                const float g0 = fmaxf(c2[0] + b1f[et], 0.f);
                const float g1 = fmaxf(c2[1] + b1f[et], 0.f);
                const float g2 = fmaxf(c2[2] + b1f[et], 0.f);
                const float g3 = fmaxf(c2[3] + b1f[et], 0.f);
                AT[et] = mfma_k16(rtp[mt][0], rtp[mt][1],
                                  trn_pk(g0, g1), trn_pk(g2, g3), AT[et]);
            }
        }

        // ---- A = AT + Bj[e&3]; valid rows d=0..3 live in q==0 lanes
        if (lane < 16) {
#pragma unroll
            for (int et = 0; et < 8; et++) {
                const f32x4 v = AT[et] + Bj[et & 3];
                *(f32x4*)&s_A[(et * 16 + lane) * 4] = v;
            }
        }
        lds_fence();

        // ---- D[e][m] = dot(A[e], A[m]), m<16; coalesced float4 stores
        {
            const int m0 = (lane & 3) * 4;
            const int er = lane >> 2;
            f32x4 Am[4];
#pragma unroll
            for (int t = 0; t < 4; t++) Am[t] = *(const f32x4*)&s_A[(m0 + t) * 4];
            float* op = out + (size_t)atom * 2048;
#pragma unroll
            for (int g = 0; g < 8; g++) {
                const int e = g * 16 + er;
                const f32x4 Ae = *(const f32x4*)&s_A[e * 4];
                f32x4 o;
                o[0] = Ae[0]*Am[0][0] + Ae[1]*Am[0][1] + Ae[2]*Am[0][2] + Ae[3]*Am[0][3];
                o[1] = Ae[0]*Am[1][0] + Ae[1]*Am[1][1] + Ae[2]*Am[1][2] + Ae[3]*Am[1][3];
                o[2] = Ae[0]*Am[2][0] + Ae[1]*Am[2][1] + Ae[2]*Am[2][2] + Ae[3]*Am[2][3];
                o[3] = Ae[0]*Am[3][0] + Ae[1]*Am[3][1] + Ae[2]*Am[3][2] + Ae[3]*Am[3][3];
                *(f32x4*)&op[e * 16 + m0] = o;
            }
        }

        // rotate prefetched geometry state
        cnb = nnb; ccx = ncx; ccy = ncy; ccz = ncz; cct = nct;
        cpx = npx; cpy = npy; cpz = npz; cntp = nntp;
    }
}

extern "C" void kernel_launch(void* const* d_in, const int* in_sizes, int n_in,
                              void* d_out, int out_size, void* d_ws, size_t ws_size,
                              hipStream_t stream) {
    (void)in_sizes; (void)n_in; (void)out_size; (void)ws_size;
    const float* inputs      = (const float*)d_in[0];
    const int*   input_types = (const int*)d_in[1];
    const int*   neigh_list  = (const int*)d_in[2];
    const float* length      = (const float*)d_in[3];
    const float* ew0 = (const float*)d_in[4];
    const float* eb0 = (const float*)d_in[5];
    const float* ew1 = (const float*)d_in[6];
    const float* eb1 = (const float*)d_in[7];
    const float* fw0 = (const float*)d_in[8];
    const float* fb0 = (const float*)d_in[9];
    const float* fw1 = (const float*)d_in[10];
    const float* fb1 = (const float*)d_in[11];
    const float* gw0 = (const float*)d_in[12];
    const float* gb0 = (const float*)d_in[13];
    const float* gw1 = (const float*)d_in[14];
    const float* gb1 = (const float*)d_in[15];
    float* out = (float*)d_out;

    unsigned* td_pk = (unsigned*)d_ws;                                 // 64 u32
    unsigned short* w0t = (unsigned short*)((char*)d_ws + 512);        // 2048 bf16
    unsigned short* w1t = (unsigned short*)((char*)d_ws + 512 + 4096); // 8192 bf16

    hipLaunchKernelGGL(prep_kernel, dim3(1), dim3(256), 0, stream,
                       ew0, eb0, ew1, eb1, fw0, fb0, fw1, fb1, gw0, gw1,
                       td_pk, w0t, w1t);

    const int nblocks = (S_DIM * N_DIM) / APW;   // 4096
    hipLaunchKernelGGL(descr_mfma, dim3(nblocks), dim3(64), 0, stream,
                       inputs, input_types, neigh_list, length,
                       gb0, gb1, td_pk, w0t, w1t, out);
}

// Round 4
// 222.485 us; speedup vs baseline: 1.6807x; 1.6807x over previous
//
#include <hip/hip_runtime.h>
#include <math.h>

#define S_DIM 8
#define N_DIM 2048
#define K_DIM 64
#define APW 4          // atoms per wave (= per 64-thread block)
#define ST_ST 40       // s_tilde row stride, bf16 units (80 B rows, 16B-aligned)
#define ST_H1 72       // h1 chunk row stride, bf16 units (144 B rows, 16B-aligned)

typedef __attribute__((ext_vector_type(8))) short bf16x8;
typedef __attribute__((ext_vector_type(4))) float f32x4;
typedef __attribute__((ext_vector_type(4))) int   i32x4;

__device__ __forceinline__ unsigned asu(float x) {
    union { float f; unsigned u; } v; v.f = x; return v.u;
}
__device__ __forceinline__ unsigned short f2bf(float x) {
    unsigned u = asu(x);
    return (unsigned short)((u + 0x7FFFu + ((u >> 16) & 1u)) >> 16);
}
__device__ __forceinline__ float bf2f(unsigned short h) {
    union { unsigned u; float f; } v; v.u = ((unsigned)h) << 16; return v.f;
}
// round-nearest-even packed pair (x -> lo16, y -> hi16) — integer-ALU form,
// bit-identical to the measured-correct round-0 baseline (absmax 128).
// (v_cvt_pk_bf16_f32 inline asm was the round-2 absmax-524 bug: not RNE.)
__device__ __forceinline__ unsigned rne_pk(float x, float y) {
    unsigned ux = asu(x), uy = asu(y);
    return ((ux + 0x7FFFu + ((ux >> 16) & 1u)) >> 16) |
           ((uy + 0x7FFFu + ((uy >> 16) & 1u)) & 0xFFFF0000u);
}
// truncation packed pair (cheap; used only for MFMA operand packs, as round-0)
__device__ __forceinline__ unsigned trn_pk(float x, float y) {
    return (asu(x) >> 16) | (asu(y) & 0xFFFF0000u);
}
// LDS-only fence: orders intra-wave cross-lane LDS traffic WITHOUT draining
// vmcnt. Blocks are single-wave, so __syncthreads' s_barrier + vmcnt(0) drain
// (which serialized output stores + killed gather prefetch every atom) is
// unnecessary; lgkmcnt(0) + a compiler memory barrier is sufficient.
// Correctness proven: round-3 passed with absmax bit-identical to baseline.
__device__ __forceinline__ void lds_fence() {
    asm volatile("s_waitcnt lgkmcnt(0)" ::: "memory");
    __builtin_amdgcn_sched_barrier(0);
}
// K<=16 MFMA from two packed bf16-pair dwords per operand (zero-padded K=32).
__device__ __forceinline__ f32x4 mfma_k16(unsigned a0, unsigned a1,
                                          unsigned b0, unsigned b1, f32x4 c) {
    union { i32x4 i; bf16x8 b; } ua, ub;
    ua.i = (i32x4){(int)a0, (int)a1, 0, 0};
    ub.i = (i32x4){(int)b0, (int)b1, 0, 0};
    return __builtin_amdgcn_mfma_f32_16x16x32_bf16(ua.b, ub.b, c, 0, 0, 0);
}

// ---------------------------------------------------------------------------
// Prep: packed td table (4 pairs x 16 u32 of bf16-pairs) + bf16 weights.
// ---------------------------------------------------------------------------
__global__ __launch_bounds__(256) void prep_kernel(
        const float* __restrict__ ew0, const float* __restrict__ eb0,
        const float* __restrict__ ew1, const float* __restrict__ eb1,
        const float* __restrict__ fw0, const float* __restrict__ fb0,
        const float* __restrict__ fw1, const float* __restrict__ fb1,
        const float* __restrict__ gw0, const float* __restrict__ gw1,
        unsigned* __restrict__ td_pk,
        unsigned short* __restrict__ w0t, unsigned short* __restrict__ w1t) {
    __shared__ float l_ew0[32], l_eb0[16], l_ew1[512], l_eb1[32];
    __shared__ float l_fw0[1024], l_fb0[32], l_fw1[992], l_fb1[31];
    __shared__ float l_h[4][2][16];
    __shared__ float l_tv[4][32];
    __shared__ float l_f1[4][32];
    __shared__ float l_td[4][32];

    const int tid = threadIdx.x;
    if (tid < 32) l_ew0[tid] = ew0[tid];
    if (tid < 16) l_eb0[tid] = eb0[tid];
    for (int i = tid; i < 512; i += 256) l_ew1[i] = ew1[i];
    if (tid < 32) l_eb1[tid] = eb1[tid];
    for (int i = tid; i < 1024; i += 256) l_fw0[i] = fw0[i];
    if (tid < 32) l_fb0[tid] = fb0[tid];
    for (int i = tid; i < 992; i += 256) l_fw1[i] = fw1[i];
    if (tid < 31) l_fb1[tid] = fb1[tid];
    __syncthreads();

    if (tid < 128) {
        const int p = tid >> 5, ord = (tid >> 4) & 1, j = tid & 15;
        const float c = (float)(p >> 1), t = (float)(p & 1);
        const float x0 = ord ? t : c;
        const float x1 = ord ? c : t;
        l_h[p][ord][j] = fmaxf(x0 * l_ew0[j] + x1 * l_ew0[16 + j] + l_eb0[j], 0.f);
    }
    __syncthreads();
    if (tid < 128) {
        const int p = tid >> 5, j = tid & 31;
        float acc = 0.f;
#pragma unroll
        for (int ord = 0; ord < 2; ord++) {
            float v = l_eb1[j];
#pragma unroll
            for (int i = 0; i < 16; i++) v += l_h[p][ord][i] * l_ew1[i * 32 + j];
            acc += fmaxf(v, 0.f);
        }
        l_tv[p][j] = acc;
    }
    __syncthreads();
    if (tid < 128) {
        const int p = tid >> 5, j = tid & 31;
        float v = l_fb0[j];
#pragma unroll
        for (int i = 0; i < 32; i++) v += l_tv[p][i] * l_fw0[i * 32 + j];
        l_f1[p][j] = fmaxf(v, 0.f);
    }
    __syncthreads();
    if (tid < 128) {
        const int p = tid >> 5, j = tid & 31;
        if (j < 31) {
            float v = l_fb1[j];
#pragma unroll
            for (int i = 0; i < 32; i++) v += l_f1[p][i] * l_fw1[i * 31 + j];
            l_td[p][j] = fmaxf(v, 0.f);
        } else {
            l_td[p][31] = 0.f;
        }
    }
    __syncthreads();
    if (tid < 64) {   // pack: td_pk[p*16+i] = bf(td[2i]) | bf(td[2i+1])<<16
        const int p = tid >> 4, i = tid & 15;
        const unsigned lo = f2bf(l_td[p][2 * i]);
        const unsigned hi = (i == 15) ? 0u : (unsigned)f2bf(l_td[p][2 * i + 1]);
        td_pk[tid] = lo | (hi << 16);
    }

    for (int idx = tid; idx < 2048; idx += 256) {   // W0T[j*32+i] = gw0[i][j]
        const int j = idx >> 5, i = idx & 31;
        w0t[idx] = f2bf(gw0[i * 64 + j]);
    }
    for (int idx = tid; idx < 8192; idx += 256) {   // W1T[e*64+j] = gw1[j][e]
        const int e = idx >> 6, j = idx & 63;
        w1t[idx] = f2bf(gw1[j * 128 + e]);
    }
}

// ---------------------------------------------------------------------------
// Main: one wave per block, 4 atoms per wave, software-pipelined geometry.
// No __syncthreads anywhere: single-wave blocks only need LDS-order fences,
// so output stores and next-atom gathers stay in flight across atoms.
// h1 is produced/consumed in 16-row double-buffered chunks (LDS 15.9->11.0KB).
// __launch_bounds__(64,2): the (64,3) attempt cut the VGPR budget to 84 and
// spilled w1f/accumulators to scratch (FETCH 3.4->314 MB, dur 79->226 us).
// The register file IS the occupancy constraint here — do not tighten it.
// ---------------------------------------------------------------------------
__global__ __launch_bounds__(64, 2) void descr_mfma(
    const float* __restrict__ inputs, const int* __restrict__ input_types,
    const int* __restrict__ neigh_list, const float* __restrict__ length,
    const float* __restrict__ gb0, const float* __restrict__ gb1,
    const unsigned* __restrict__ td_pk, const unsigned short* __restrict__ w0t,
    const unsigned short* __restrict__ w1t, float* __restrict__ out)
{
    __shared__ __align__(16) unsigned short s_st[64 * ST_ST];      // 5.0 KB; s_A overlay
    __shared__ __align__(16) unsigned short s_h1[2][16 * ST_H1];   // 4.5 KB dbuf chunks
    __shared__ __align__(16) float s_rtT[4 * 68];                  // 1.1 KB
    __shared__ unsigned s_tdpk[64];
    float* s_A = (float*)s_st;                                     // st dead after L1

    const int lane = threadIdx.x;
    const int l15 = lane & 15;
    const int q = lane >> 4;
    const int abase = blockIdx.x * APW;
    const int sidx = abase >> 11;      // all 4 atoms of a block share the same s

    // static weight fragments (B-layout)
    bf16x8 w0f[4];
#pragma unroll
    for (int nt = 0; nt < 4; nt++)
        w0f[nt] = *(const bf16x8*)&w0t[(nt * 16 + l15) * 32 + q * 8];
    bf16x8 w1f[8][2];
#pragma unroll
    for (int et = 0; et < 8; et++) {
        w1f[et][0] = *(const bf16x8*)&w1t[(et * 16 + l15) * 64 + q * 8];
        w1f[et][1] = *(const bf16x8*)&w1t[(et * 16 + l15) * 64 + 32 + q * 8];
    }
    float b0f[4], b1f[8];
#pragma unroll
    for (int jt = 0; jt < 4; jt++) b0f[jt] = gb0[jt * 16 + l15];
#pragma unroll
    for (int et = 0; et < 8; et++) b1f[et] = gb1[et * 16 + l15];
    s_tdpk[lane] = td_pk[lane];
    const float Lx = length[0], Ly = length[1], Lz = length[2];
    const float iLx = 1.f / Lx, iLy = 1.f / Ly, iLz = 1.f / Lz;
    const f32x4 zf = {0.f, 0.f, 0.f, 0.f};

    // geometry state for the CURRENT atom (loaded one iteration ahead)
    int   cnb  = neigh_list[abase * K_DIM + lane];
    float ccx  = inputs[abase * 3 + 0];
    float ccy  = inputs[abase * 3 + 1];
    float ccz  = inputs[abase * 3 + 2];
    int   cct  = input_types[abase];
    int   cidx0 = cnb < 0 ? 0 : cnb;
    float cpx  = inputs[(sidx * N_DIM + cidx0) * 3 + 0];
    float cpy  = inputs[(sidx * N_DIM + cidx0) * 3 + 1];
    float cpz  = inputs[(sidx * N_DIM + cidx0) * 3 + 2];
    int   cntp = input_types[sidx * N_DIM + cidx0];

    for (int aa = 0; aa < APW; aa++) {
        const int atom = abase + aa;
        const bool pf = (aa + 1 < APW);

        // ---- stage-A prefetch for next atom (independent addresses, issue now)
        int nnb = 0, nct = 0; float ncx = 0.f, ncy = 0.f, ncz = 0.f;
        if (pf) {
            nnb = neigh_list[(atom + 1) * K_DIM + lane];
            ncx = inputs[(atom + 1) * 3 + 0];
            ncy = inputs[(atom + 1) * 3 + 1];
            ncz = inputs[(atom + 1) * 3 + 2];
            nct = input_types[atom + 1];
        }

        lds_fence();   // s_st/s_rtT overwrite vs previous atom's reads (incl. s_A)

        // ---- geometry (all operands already in registers)
        {
            const bool msk = cnb < 0;
            float dx = cpx - ccx;
            float dy = cpy - ccy;
            float dz = cpz - ccz;
            dx -= Lx * rintf(dx * iLx);
            dy -= Ly * rintf(dy * iLy);
            dz -= Lz * rintf(dz * iLz);
            const float rsq = dx * dx + dy * dy + dz * dz;
            const float r = sqrtf(rsq > 0.f ? rsq : 1.f);
            const float inv = 1.f / r;
            float sw;
            if (r < 6.f) sw = inv;
            else if (r < 12.f) {
                const float u = (r - 6.f) * (1.f / 6.f);
                sw = inv * (0.5f * __cosf(3.14159265358979323846f * u) + 0.5f);
            } else sw = 0.f;
            const bool valid = (!msk) && (rsq > 0.f);
            const float sij = valid ? sw : 0.f;
            const float f = sij * inv;
            s_rtT[0 * 68 + lane] = sij;
            s_rtT[1 * 68 + lane] = dx * f;
            s_rtT[2 * 68 + lane] = dy * f;
            s_rtT[3 * 68 + lane] = dz * f;

            const unsigned* tdr = &s_tdpk[(cct * 2 + cntp) * 16];
            const unsigned zmask = msk ? 0u : 0xFFFFFFFFu;
            unsigned* strow = (unsigned*)&s_st[lane * ST_ST];
#pragma unroll
            for (int i = 0; i < 15; i++) strow[i] = tdr[i] & zmask;
            strow[15] = (tdr[15] & zmask & 0xFFFFu) | (((unsigned)f2bf(sij)) << 16);
            strow[16] = 0; strow[17] = 0; strow[18] = 0; strow[19] = 0;
        }
        lds_fence();

        // ---- rt^T fragments (A-operand of Bj/AT steps), packed RNE pairs
        unsigned rtp[4][2];
#pragma unroll
        for (int a = 0; a < 4; a++) {
            const f32x4 rv = *(const f32x4*)&s_rtT[(l15 & 3) * 68 + a * 16 + q * 4];
            rtp[a][0] = rne_pk(rv[0], rv[1]);
            rtp[a][1] = rne_pk(rv[2], rv[3]);
        }

        int nidx = 0, nntp = 0; float npx = 0.f, npy = 0.f, npz = 0.f;
        f32x4 Bj[4] = {zf, zf, zf, zf};
        f32x4 AT[8] = {zf, zf, zf, zf, zf, zf, zf, zf};

        // ---- fused per-16-row chunk: L1 -> h1 chunk -> Bj ; then L2 -> AT
#pragma unroll
        for (int mt = 0; mt < 4; mt++) {
            unsigned short* h1c = s_h1[mt & 1];
            const bf16x8 afr = *(const bf16x8*)&s_st[(mt * 16 + l15) * ST_ST + q * 8];
            f32x4 c1[4];
#pragma unroll
            for (int jt = 0; jt < 4; jt++)
                c1[jt] = __builtin_amdgcn_mfma_f32_16x16x32_bf16(afr, w0f[jt], zf, 0, 0, 0);
#pragma unroll
            for (int jt = 0; jt < 4; jt++) {
                float hv[4];
#pragma unroll
                for (int reg = 0; reg < 4; reg++) {
                    const int k = mt * 16 + q * 4 + reg;
                    const float rres = bf2f(s_st[k * ST_ST + (jt & 1) * 16 + l15]);
                    hv[reg] = fmaxf(c1[jt][reg] + b0f[jt], 0.f) + rres;
                    h1c[(q * 4 + reg) * ST_H1 + jt * 16 + l15] = f2bf(hv[reg]);
                }
                Bj[jt] = mfma_k16(rtp[mt][0], rtp[mt][1],
                                  trn_pk(hv[0], hv[1]), trn_pk(hv[2], hv[3]), Bj[jt]);
            }
            // stage-B prefetch (gathers dependent on stage-A nnb): issue once,
            // ~3 chunks + D-phase of slack before consumption next iteration
            if (mt == 0 && pf) {
                nidx = nnb < 0 ? 0 : nnb;
                const int nbase = (sidx * N_DIM + nidx) * 3;
                npx = inputs[nbase + 0];
                npy = inputs[nbase + 1];
                npz = inputs[nbase + 2];
                nntp = input_types[sidx * N_DIM + nidx];
            }
            lds_fence();   // chunk write -> read handoff (dbuf: no end-of-chunk fence)

            const bf16x8 a0 = *(const bf16x8*)&h1c[l15 * ST_H1 + q * 8];
            const bf16x8 a1 = *(const bf16x8*)&h1c[l15 * ST_H1 + 32 + q * 8];
#pragma unroll
            for (int et = 0; et < 8; et++) {
                f32x4 c2 = __builtin_amdgcn_mfma_f32_16x16x32_bf16(a0, w1f[et][0], zf, 0, 0, 0);
                c2 = __builtin_amdgcn_mfma_f32_16x16x32_bf16(a1, w1f[et][1], c2, 0, 0, 0);
                const float g0 = fmaxf(c2[0] + b1f[et], 0.f);
                const float g1 = fmaxf(c2[1] + b1f[et], 0.f);
                const float g2 = fmaxf(c2[2] + b1f[et], 0.f);
                const float g3 = fmaxf(c2[3] + b1f[et], 0.f);
                AT[et] = mfma_k16(rtp[mt][0], rtp[mt][1],
                                  trn_pk(g0, g1), trn_pk(g2, g3), AT[et]);
            }
        }

        // ---- A = AT + Bj[e&3]; valid rows d=0..3 live in q==0 lanes
        if (lane < 16) {
#pragma unroll
            for (int et = 0; et < 8; et++) {
                const f32x4 v = AT[et] + Bj[et & 3];
                *(f32x4*)&s_A[(et * 16 + lane) * 4] = v;
            }
        }
        lds_fence();

        // ---- D[e][m] = dot(A[e], A[m]), m<16; coalesced float4 stores
        {
            const int m0 = (lane & 3) * 4;
            const int er = lane >> 2;
            f32x4 Am[4];
#pragma unroll
            for (int t = 0; t < 4; t++) Am[t] = *(const f32x4*)&s_A[(m0 + t) * 4];
            float* op = out + (size_t)atom * 2048;
#pragma unroll
            for (int g = 0; g < 8; g++) {
                const int e = g * 16 + er;
                const f32x4 Ae = *(const f32x4*)&s_A[e * 4];
                f32x4 o;
                o[0] = Ae[0]*Am[0][0] + Ae[1]*Am[0][1] + Ae[2]*Am[0][2] + Ae[3]*Am[0][3];
                o[1] = Ae[0]*Am[1][0] + Ae[1]*Am[1][1] + Ae[2]*Am[1][2] + Ae[3]*Am[1][3];
                o[2] = Ae[0]*Am[2][0] + Ae[1]*Am[2][1] + Ae[2]*Am[2][2] + Ae[3]*Am[2][3];
                o[3] = Ae[0]*Am[3][0] + Ae[1]*Am[3][1] + Ae[2]*Am[3][2] + Ae[3]*Am[3][3];
                *(f32x4*)&op[e * 16 + m0] = o;
            }
        }

        // rotate prefetched geometry state
        cnb = nnb; ccx = ncx; ccy = ncy; ccz = ncz; cct = nct;
        cpx = npx; cpy = npy; cpz = npz; cntp = nntp;
    }
}

extern "C" void kernel_launch(void* const* d_in, const int* in_sizes, int n_in,
                              void* d_out, int out_size, void* d_ws, size_t ws_size,
                              hipStream_t stream) {
    (void)in_sizes; (void)n_in; (void)out_size; (void)ws_size;
    const float* inputs      = (const float*)d_in[0];
    const int*   input_types = (const int*)d_in[1];
    const int*   neigh_list  = (const int*)d_in[2];
    const float* length      = (const float*)d_in[3];
    const float* ew0 = (const float*)d_in[4];
    const float* eb0 = (const float*)d_in[5];
    const float* ew1 = (const float*)d_in[6];
    const float* eb1 = (const float*)d_in[7];
    const float* fw0 = (const float*)d_in[8];
    const float* fb0 = (const float*)d_in[9];
    const float* fw1 = (const float*)d_in[10];
    const float* fb1 = (const float*)d_in[11];
    const float* gw0 = (const float*)d_in[12];
    const float* gb0 = (const float*)d_in[13];
    const float* gw1 = (const float*)d_in[14];
    const float* gb1 = (const float*)d_in[15];
    float* out = (float*)d_out;

    unsigned* td_pk = (unsigned*)d_ws;                                 // 64 u32
    unsigned short* w0t = (unsigned short*)((char*)d_ws + 512);        // 2048 bf16
    unsigned short* w1t = (unsigned short*)((char*)d_ws + 512 + 4096); // 8192 bf16

    hipLaunchKernelGGL(prep_kernel, dim3(1), dim3(256), 0, stream,
                       ew0, eb0, ew1, eb1, fw0, fb0, fw1, fb1, gw0, gw1,
                       td_pk, w0t, w1t);

    const int nblocks = (S_DIM * N_DIM) / APW;   // 4096
    hipLaunchKernelGGL(descr_mfma, dim3(nblocks), dim3(64), 0, stream,
                       inputs, input_types, neigh_list, length,
                       gb0, gb1, td_pk, w0t, w1t, out);
}

// Round 6
// 218.908 us; speedup vs baseline: 1.7081x; 1.0163x over previous
//
#include <hip/hip_runtime.h>
#include <math.h>

#define S_DIM 8
#define N_DIM 2048
#define K_DIM 64
#define APW 4          // atoms per wave (= per 64-thread block)
#define ST_ST 40       // s_tilde row stride, bf16 units (80 B rows, 16B-aligned)
// h1 tile buffer geometry: 4x16 bf16 tiles (128 B) + 16 B pad, [q_t][jt] grid
#define TQ 144         // tile stride, bytes (128 data + 16 pad; 16B-aligned)
#define TJ (4 * TQ)    // jt stride (4 q-tiles)
#define H1CH (4 * TJ)  // one mt-chunk: 16 tiles = 2304 B

typedef __attribute__((ext_vector_type(8))) short bf16x8;
typedef __attribute__((ext_vector_type(4))) float f32x4;
typedef __attribute__((ext_vector_type(4))) int   i32x4;
typedef __attribute__((ext_vector_type(2))) int   i32x2;

__device__ __forceinline__ unsigned asu(float x) {
    union { float f; unsigned u; } v; v.f = x; return v.u;
}
__device__ __forceinline__ unsigned short f2bf(float x) {
    unsigned u = asu(x);
    return (unsigned short)((u + 0x7FFFu + ((u >> 16) & 1u)) >> 16);
}
// bf16 halves of a packed dword -> f32 (1 VALU op each)
__device__ __forceinline__ float lo16f(int d) {
    union { unsigned u; float f; } v; v.u = ((unsigned)d) << 16; return v.f;
}
__device__ __forceinline__ float hi16f(int d) {
    union { unsigned u; float f; } v; v.u = ((unsigned)d) & 0xFFFF0000u; return v.f;
}
// round-nearest-even packed pair (x -> lo16, y -> hi16) — integer-ALU form,
// bit-identical to the measured-correct baseline. (v_cvt_pk_bf16_f32 was the
// round-2 absmax-524 bug: not RNE on gfx950.)
__device__ __forceinline__ unsigned rne_pk(float x, float y) {
    unsigned ux = asu(x), uy = asu(y);
    return ((ux + 0x7FFFu + ((ux >> 16) & 1u)) >> 16) |
           ((uy + 0x7FFFu + ((uy >> 16) & 1u)) & 0xFFFF0000u);
}
// truncation packed pair (cheap; used only for L2's g MFMA operand, as baseline)
__device__ __forceinline__ unsigned trn_pk(float x, float y) {
    return (asu(x) >> 16) | (asu(y) & 0xFFFF0000u);
}
// LDS-only fence (single-wave blocks): orders cross-lane LDS traffic without
// draining vmcnt. Correctness proven in rounds 3/4 (absmax == baseline).
__device__ __forceinline__ void lds_fence() {
    asm volatile("s_waitcnt lgkmcnt(0)" ::: "memory");
    __builtin_amdgcn_sched_barrier(0);
}
// K<=16 MFMA from two packed bf16-pair dwords per operand (zero-padded K=32).
__device__ __forceinline__ f32x4 mfma_k16(unsigned a0, unsigned a1,
                                          unsigned b0, unsigned b1, f32x4 c) {
    union { i32x4 i; bf16x8 b; } ua, ub;
    ua.i = (i32x4){(int)a0, (int)a1, 0, 0};
    ub.i = (i32x4){(int)b0, (int)b1, 0, 0};
    return __builtin_amdgcn_mfma_f32_16x16x32_bf16(ua.b, ub.b, c, 0, 0, 0);
}

// ---------------------------------------------------------------------------
// Prep: packed td table (4 pairs x 16 u32 of bf16-pairs) + bf16 weights.
// ---------------------------------------------------------------------------
__global__ __launch_bounds__(256) void prep_kernel(
        const float* __restrict__ ew0, const float* __restrict__ eb0,
        const float* __restrict__ ew1, const float* __restrict__ eb1,
        const float* __restrict__ fw0, const float* __restrict__ fb0,
        const float* __restrict__ fw1, const float* __restrict__ fb1,
        const float* __restrict__ gw0, const float* __restrict__ gw1,
        unsigned* __restrict__ td_pk,
        unsigned short* __restrict__ w0t, unsigned short* __restrict__ w1t) {
    __shared__ float l_ew0[32], l_eb0[16], l_ew1[512], l_eb1[32];
    __shared__ float l_fw0[1024], l_fb0[32], l_fw1[992], l_fb1[31];
    __shared__ float l_h[4][2][16];
    __shared__ float l_tv[4][32];
    __shared__ float l_f1[4][32];
    __shared__ float l_td[4][32];

    const int tid = threadIdx.x;
    if (tid < 32) l_ew0[tid] = ew0[tid];
    if (tid < 16) l_eb0[tid] = eb0[tid];
    for (int i = tid; i < 512; i += 256) l_ew1[i] = ew1[i];
    if (tid < 32) l_eb1[tid] = eb1[tid];
    for (int i = tid; i < 1024; i += 256) l_fw0[i] = fw0[i];
    if (tid < 32) l_fb0[tid] = fb0[tid];
    for (int i = tid; i < 992; i += 256) l_fw1[i] = fw1[i];
    if (tid < 31) l_fb1[tid] = fb1[tid];
    __syncthreads();

    if (tid < 128) {
        const int p = tid >> 5, ord = (tid >> 4) & 1, j = tid & 15;
        const float c = (float)(p >> 1), t = (float)(p & 1);
        const float x0 = ord ? t : c;
        const float x1 = ord ? c : t;
        l_h[p][ord][j] = fmaxf(x0 * l_ew0[j] + x1 * l_ew0[16 + j] + l_eb0[j], 0.f);
    }
    __syncthreads();
    if (tid < 128) {
        const int p = tid >> 5, j = tid & 31;
        float acc = 0.f;
#pragma unroll
        for (int ord = 0; ord < 2; ord++) {
            float v = l_eb1[j];
#pragma unroll
            for (int i = 0; i < 16; i++) v += l_h[p][ord][i] * l_ew1[i * 32 + j];
            acc += fmaxf(v, 0.f);
        }
        l_tv[p][j] = acc;
    }
    __syncthreads();
    if (tid < 128) {
        const int p = tid >> 5, j = tid & 31;
        float v = l_fb0[j];
#pragma unroll
        for (int i = 0; i < 32; i++) v += l_tv[p][i] * l_fw0[i * 32 + j];
        l_f1[p][j] = fmaxf(v, 0.f);
    }
    __syncthreads();
    if (tid < 128) {
        const int p = tid >> 5, j = tid & 31;
        if (j < 31) {
            float v = l_fb1[j];
#pragma unroll
            for (int i = 0; i < 32; i++) v += l_f1[p][i] * l_fw1[i * 31 + j];
            l_td[p][j] = fmaxf(v, 0.f);
        } else {
            l_td[p][31] = 0.f;
        }
    }
    __syncthreads();
    if (tid < 64) {   // pack: td_pk[p*16+i] = bf(td[2i]) | bf(td[2i+1])<<16
        const int p = tid >> 4, i = tid & 15;
        const unsigned lo = f2bf(l_td[p][2 * i]);
        const unsigned hi = (i == 15) ? 0u : (unsigned)f2bf(l_td[p][2 * i + 1]);
        td_pk[tid] = lo | (hi << 16);
    }

    for (int idx = tid; idx < 2048; idx += 256) {   // W0T[j*32+i] = gw0[i][j]
        const int j = idx >> 5, i = idx & 31;
        w0t[idx] = f2bf(gw0[i * 64 + j]);
    }
    for (int idx = tid; idx < 8192; idx += 256) {   // W1T[e*64+j] = gw1[j][e]
        const int e = idx >> 6, j = idx & 63;
        w1t[idx] = f2bf(gw1[j * 128 + e]);
    }
}

// ---------------------------------------------------------------------------
// Main: one wave per block, 4 atoms, pipelined geometry.
// L1 computed TRANSPOSED — mfma(W0^T-frag, st-frag) gives lane
// h1[k=mt*16+l15][j=jt*16+q*4+reg] with the SAME register fragments.
//  * residual read: contiguous ds_read_b64 from own st row
//  * h1 store: 4 ds_write_b64/mt into 4x16 tiles
//  * Bj operand: ds_read_b64_tr_b16 — COOPERATIVE model (round-5 lesson):
//    within a 16-lane group, lane p's addr supplies chunk p (8 B); the 16
//    chunks form a 4x16 bf16 tile (lane p -> row p>>2, col-quad p&3); HW
//    hands lane i column i. So lane addr = natural row-major chunk addr of
//    the tile, NOT col*2. (round-5's `+l15*2` was the absmax-15888 bug.)
//  * L2 A-frag: plain ds_read_b128 from the same tiles
// __launch_bounds__(64,2): (64,3) spilled to scratch in R3 — do not tighten.
// ---------------------------------------------------------------------------
__global__ __launch_bounds__(64, 2) void descr_mfma(
    const float* __restrict__ inputs, const int* __restrict__ input_types,
    const int* __restrict__ neigh_list, const float* __restrict__ length,
    const float* __restrict__ gb0, const float* __restrict__ gb1,
    const unsigned* __restrict__ td_pk, const unsigned short* __restrict__ w0t,
    const unsigned short* __restrict__ w1t, float* __restrict__ out)
{
    __shared__ __align__(16) unsigned short s_st[64 * ST_ST];  // 5.0 KB; s_A overlay
    __shared__ __align__(16) char s_h1t[2 * H1CH];             // 4.5 KB tile dbuf
    __shared__ __align__(16) float s_rtT[4 * 68];              // 1.1 KB
    __shared__ unsigned s_tdpk[64];
    float* s_A = (float*)s_st;                                 // st dead after L1/L2

    const int lane = threadIdx.x;
    const int l15 = lane & 15;
    const int q = lane >> 4;
    const int abase = blockIdx.x * APW;
    const int sidx = abase >> 11;      // all 4 atoms of a block share the same s

    // static weight fragments. Content W0T[j][i] serves as A-operand (W0^T) for
    // the transposed L1; w1f unchanged as L2 B-operand.
    bf16x8 w0f[4];
#pragma unroll
    for (int nt = 0; nt < 4; nt++)
        w0f[nt] = *(const bf16x8*)&w0t[(nt * 16 + l15) * 32 + q * 8];
    bf16x8 w1f[8][2];
#pragma unroll
    for (int et = 0; et < 8; et++) {
        w1f[et][0] = *(const bf16x8*)&w1t[(et * 16 + l15) * 64 + q * 8];
        w1f[et][1] = *(const bf16x8*)&w1t[(et * 16 + l15) * 64 + 32 + q * 8];
    }
    // bias b0 indexed by j = jt*16 + q*4 + reg (transposed L1 epilogue)
    f32x4 b0v[4];
#pragma unroll
    for (int jt = 0; jt < 4; jt++)
        b0v[jt] = *(const f32x4*)&gb0[jt * 16 + q * 4];
    float b1f[8];
#pragma unroll
    for (int et = 0; et < 8; et++) b1f[et] = gb1[et * 16 + l15];
    s_tdpk[lane] = td_pk[lane];
    const float Lx = length[0], Ly = length[1], Lz = length[2];
    const float iLx = 1.f / Lx, iLy = 1.f / Ly, iLz = 1.f / Lz;
    const f32x4 zf = {0.f, 0.f, 0.f, 0.f};

    // h1 tile buffer addressing (byte offsets; low 32 bits of flat LDS addr)
    const unsigned h1u  = (unsigned)(unsigned long long)(const void*)&s_h1t[0];
    const int wroff = (l15 >> 2) * TQ + (l15 & 3) * 32 + q * 8;          // write
    // tr read: lane supplies chunk (row l15>>2, col-quad l15&3) of tile (q, jt)
    const unsigned troff = h1u + (unsigned)(q * TQ + (l15 >> 2) * 32 + (l15 & 3) * 8);
    const int aoff  = (l15 >> 2) * TQ + (l15 & 3) * 32 + (q & 1) * 16;   // L2 read

    // geometry state for the CURRENT atom (loaded one iteration ahead)
    int   cnb  = neigh_list[abase * K_DIM + lane];
    float ccx  = inputs[abase * 3 + 0];
    float ccy  = inputs[abase * 3 + 1];
    float ccz  = inputs[abase * 3 + 2];
    int   cct  = input_types[abase];
    int   cidx0 = cnb < 0 ? 0 : cnb;
    float cpx  = inputs[(sidx * N_DIM + cidx0) * 3 + 0];
    float cpy  = inputs[(sidx * N_DIM + cidx0) * 3 + 1];
    float cpz  = inputs[(sidx * N_DIM + cidx0) * 3 + 2];
    int   cntp = input_types[sidx * N_DIM + cidx0];

    for (int aa = 0; aa < APW; aa++) {
        const int atom = abase + aa;
        const bool pf = (aa + 1 < APW);

        // ---- stage-A prefetch for next atom
        int nnb = 0, nct = 0; float ncx = 0.f, ncy = 0.f, ncz = 0.f;
        if (pf) {
            nnb = neigh_list[(atom + 1) * K_DIM + lane];
            ncx = inputs[(atom + 1) * 3 + 0];
            ncy = inputs[(atom + 1) * 3 + 1];
            ncz = inputs[(atom + 1) * 3 + 2];
            nct = input_types[atom + 1];
        }

        lds_fence();   // s_st/s_rtT overwrite vs previous atom's reads (incl. s_A)

        // ---- geometry (operands in registers)
        {
            const bool msk = cnb < 0;
            float dx = cpx - ccx;
            float dy = cpy - ccy;
            float dz = cpz - ccz;
            dx -= Lx * rintf(dx * iLx);
            dy -= Ly * rintf(dy * iLy);
            dz -= Lz * rintf(dz * iLz);
            const float rsq = dx * dx + dy * dy + dz * dz;
            const float r = sqrtf(rsq > 0.f ? rsq : 1.f);
            const float inv = 1.f / r;
            float sw;
            if (r < 6.f) sw = inv;
            else if (r < 12.f) {
                const float u = (r - 6.f) * (1.f / 6.f);
                sw = inv * (0.5f * __cosf(3.14159265358979323846f * u) + 0.5f);
            } else sw = 0.f;
            const bool valid = (!msk) && (rsq > 0.f);
            const float sij = valid ? sw : 0.f;
            const float f = sij * inv;
            s_rtT[0 * 68 + lane] = sij;
            s_rtT[1 * 68 + lane] = dx * f;
            s_rtT[2 * 68 + lane] = dy * f;
            s_rtT[3 * 68 + lane] = dz * f;

            const unsigned* tdr = &s_tdpk[(cct * 2 + cntp) * 16];
            const unsigned zmask = msk ? 0u : 0xFFFFFFFFu;
            unsigned* strow = (unsigned*)&s_st[lane * ST_ST];
#pragma unroll
            for (int i = 0; i < 15; i++) strow[i] = tdr[i] & zmask;
            strow[15] = (tdr[15] & zmask & 0xFFFFu) | (((unsigned)f2bf(sij)) << 16);
            // pad cols 32..39 never read: no zeroing needed
        }
        lds_fence();

        // ---- rt^T fragments (A-operand of Bj/AT), packed RNE pairs
        unsigned rtp[4][2];
#pragma unroll
        for (int a = 0; a < 4; a++) {
            const f32x4 rv = *(const f32x4*)&s_rtT[(l15 & 3) * 68 + a * 16 + q * 4];
            rtp[a][0] = rne_pk(rv[0], rv[1]);
            rtp[a][1] = rne_pk(rv[2], rv[3]);
        }

        int nidx = 0, nntp = 0; float npx = 0.f, npy = 0.f, npz = 0.f;
        f32x4 Bj[4] = {zf, zf, zf, zf};
        f32x4 AT[8] = {zf, zf, zf, zf, zf, zf, zf, zf};

        // ---- per-16-k-row chunk: L1^T -> tiles -> (Bj via tr-read, L2 -> AT)
#pragma unroll
        for (int mt = 0; mt < 4; mt++) {
            const int cb = (mt & 1) * H1CH;
            // st fragment: st[mt*16+l15][q*8..+7] — B-operand of transposed L1
            const bf16x8 afr = *(const bf16x8*)&s_st[(mt * 16 + l15) * ST_ST + q * 8];
            // residual rows: st[mt*16+l15][q*4..+3] and [16+q*4..+3] (contig b64)
            const i32x2 r0 = *(const i32x2*)&s_st[(mt * 16 + l15) * ST_ST + q * 4];
            const i32x2 r1 = *(const i32x2*)&s_st[(mt * 16 + l15) * ST_ST + 16 + q * 4];

            f32x4 c1[4];
#pragma unroll
            for (int jt = 0; jt < 4; jt++)   // TRANSPOSED: A=W0^T, B=st
                c1[jt] = __builtin_amdgcn_mfma_f32_16x16x32_bf16(w0f[jt], afr, zf, 0, 0, 0);

            // epilogue: lane holds h1[k=mt*16+l15][j=jt*16+q*4+reg]
#pragma unroll
            for (int jt = 0; jt < 4; jt++) {
                const i32x2 rr = (jt & 1) ? r1 : r0;
                const float h0 = fmaxf(c1[jt][0] + b0v[jt][0], 0.f) + lo16f(rr[0]);
                const float h1 = fmaxf(c1[jt][1] + b0v[jt][1], 0.f) + hi16f(rr[0]);
                const float h2 = fmaxf(c1[jt][2] + b0v[jt][2], 0.f) + lo16f(rr[1]);
                const float h3 = fmaxf(c1[jt][3] + b0v[jt][3], 0.f) + hi16f(rr[1]);
                i32x2 pk;
                pk[0] = (int)rne_pk(h0, h1);
                pk[1] = (int)rne_pk(h2, h3);
                *(i32x2*)(s_h1t + cb + wroff + jt * TJ) = pk;
            }
            // stage-B prefetch (depends on stage-A nnb): ample slack to next use
            if (mt == 0 && pf) {
                nidx = nnb < 0 ? 0 : nnb;
                const int nbase = (sidx * N_DIM + nidx) * 3;
                npx = inputs[nbase + 0];
                npy = inputs[nbase + 1];
                npz = inputs[nbase + 2];
                nntp = input_types[sidx * N_DIM + nidx];
            }
            lds_fence();   // tile writes -> reads handoff

            // Bj B-operand: cooperative tr-read of tile (q, jt); lane i of each
            // 16-lane group receives column i: h1[mt*16+q*4+{0..3}][jt*16+i]
            i32x2 t0, t1, t2, t3;
            {
                const unsigned ta = troff + (unsigned)cb;
                asm volatile("ds_read_b64_tr_b16 %0, %1" : "=v"(t0) : "v"(ta));
                asm volatile("ds_read_b64_tr_b16 %0, %1" : "=v"(t1) : "v"(ta + TJ));
                asm volatile("ds_read_b64_tr_b16 %0, %1" : "=v"(t2) : "v"(ta + 2 * TJ));
                asm volatile("ds_read_b64_tr_b16 %0, %1" : "=v"(t3) : "v"(ta + 3 * TJ));
            }
            asm volatile("s_waitcnt lgkmcnt(0)" ::: "memory");
            __builtin_amdgcn_sched_barrier(0);   // rule #18: pin MFMAs after wait
            Bj[0] = mfma_k16(rtp[mt][0], rtp[mt][1], (unsigned)t0[0], (unsigned)t0[1], Bj[0]);
            Bj[1] = mfma_k16(rtp[mt][0], rtp[mt][1], (unsigned)t1[0], (unsigned)t1[1], Bj[1]);
            Bj[2] = mfma_k16(rtp[mt][0], rtp[mt][1], (unsigned)t2[0], (unsigned)t2[1], Bj[2]);
            Bj[3] = mfma_k16(rtp[mt][0], rtp[mt][1], (unsigned)t3[0], (unsigned)t3[1], Bj[3]);

            // L2: A-frag h1[k=mt*16+l15][j=q*8..] from tiles (plain b128)
            const bf16x8 a0 = *(const bf16x8*)(s_h1t + cb + aoff + (q >> 1) * TJ);
            const bf16x8 a1 = *(const bf16x8*)(s_h1t + cb + aoff + (2 + (q >> 1)) * TJ);
#pragma unroll
            for (int et = 0; et < 8; et++) {
                f32x4 c2 = __builtin_amdgcn_mfma_f32_16x16x32_bf16(a0, w1f[et][0], zf, 0, 0, 0);
                c2 = __builtin_amdgcn_mfma_f32_16x16x32_bf16(a1, w1f[et][1], c2, 0, 0, 0);
                const float g0 = fmaxf(c2[0] + b1f[et], 0.f);
                const float g1 = fmaxf(c2[1] + b1f[et], 0.f);
                const float g2 = fmaxf(c2[2] + b1f[et], 0.f);
                const float g3 = fmaxf(c2[3] + b1f[et], 0.f);
                AT[et] = mfma_k16(rtp[mt][0], rtp[mt][1],
                                  trn_pk(g0, g1), trn_pk(g2, g3), AT[et]);
            }
        }

        // ---- A = AT + Bj[e&3]; valid rows d=0..3 live in q==0 lanes
        if (lane < 16) {
#pragma unroll
            for (int et = 0; et < 8; et++) {
                const f32x4 v = AT[et] + Bj[et & 3];
                *(f32x4*)&s_A[(et * 16 + lane) * 4] = v;
            }
        }
        lds_fence();

        // ---- D[e][m] = dot(A[e], A[m]), m<16; coalesced float4 stores
        {
            const int m0 = (lane & 3) * 4;
            const int er = lane >> 2;
            f32x4 Am[4];
#pragma unroll
            for (int t = 0; t < 4; t++) Am[t] = *(const f32x4*)&s_A[(m0 + t) * 4];
            float* op = out + (size_t)atom * 2048;
#pragma unroll
            for (int g = 0; g < 8; g++) {
                const int e = g * 16 + er;
                const f32x4 Ae = *(const f32x4*)&s_A[e * 4];
                f32x4 o;
                o[0] = Ae[0]*Am[0][0] + Ae[1]*Am[0][1] + Ae[2]*Am[0][2] + Ae[3]*Am[0][3];
                o[1] = Ae[0]*Am[1][0] + Ae[1]*Am[1][1] + Ae[2]*Am[1][2] + Ae[3]*Am[1][3];
                o[2] = Ae[0]*Am[2][0] + Ae[1]*Am[2][1] + Ae[2]*Am[2][2] + Ae[3]*Am[2][3];
                o[3] = Ae[0]*Am[3][0] + Ae[1]*Am[3][1] + Ae[2]*Am[3][2] + Ae[3]*Am[3][3];
                *(f32x4*)&op[e * 16 + m0] = o;
            }
        }

        // rotate prefetched geometry state
        cnb = nnb; ccx = ncx; ccy = ncy; ccz = ncz; cct = nct;
        cpx = npx; cpy = npy; cpz = npz; cntp = nntp;
    }
}

extern "C" void kernel_launch(void* const* d_in, const int* in_sizes, int n_in,
                              void* d_out, int out_size, void* d_ws, size_t ws_size,
                              hipStream_t stream) {
    (void)in_sizes; (void)n_in; (void)out_size; (void)ws_size;
    const float* inputs      = (const float*)d_in[0];
    const int*   input_types = (const int*)d_in[1];
    const int*   neigh_list  = (const int*)d_in[2];
    const float* length      = (const float*)d_in[3];
    const float* ew0 = (const float*)d_in[4];
    const float* eb0 = (const float*)d_in[5];
    const float* ew1 = (const float*)d_in[6];
    const float* eb1 = (const float*)d_in[7];
    const float* fw0 = (const float*)d_in[8];
    const float* fb0 = (const float*)d_in[9];
    const float* fw1 = (const float*)d_in[10];
    const float* fb1 = (const float*)d_in[11];
    const float* gw0 = (const float*)d_in[12];
    const float* gb0 = (const float*)d_in[13];
    const float* gw1 = (const float*)d_in[14];
    const float* gb1 = (const float*)d_in[15];
    float* out = (float*)d_out;

    unsigned* td_pk = (unsigned*)d_ws;                                 // 64 u32
    unsigned short* w0t = (unsigned short*)((char*)d_ws + 512);        // 2048 bf16
    unsigned short* w1t = (unsigned short*)((char*)d_ws + 512 + 4096); // 8192 bf16

    hipLaunchKernelGGL(prep_kernel, dim3(1), dim3(256), 0, stream,
                       ew0, eb0, ew1, eb1, fw0, fb0, fw1, fb1, gw0, gw1,
                       td_pk, w0t, w1t);

    const int nblocks = (S_DIM * N_DIM) / APW;   // 4096
    hipLaunchKernelGGL(descr_mfma, dim3(nblocks), dim3(64), 0, stream,
                       inputs, input_types, neigh_list, length,
                       gb0, gb1, td_pk, w0t, w1t, out);
}